// Round 6
// baseline (1319.434 us; speedup 1.0000x reference)
//
#include <hip/hip_runtime.h>
#include <hip/hip_bf16.h>
#include <math.h>

namespace {
constexpr int CDIM   = 128;
constexpr int KCODES = 1024;
constexpr int HWSZ   = 4096;   // 64*64
constexpr int BATCH  = 16;
constexpr int NPOS   = BATCH * HWSZ;            // 65536
constexpr size_t QELEMS   = (size_t)BATCH * CDIM * HWSZ;   // 8388608
constexpr size_t IDX_OFF  = QELEMS;                        // float32 elements
constexpr size_t LOSS_OFF = IDX_OFF + (size_t)NPOS;        // 8454144
constexpr size_t PERP_OFF = LOSS_OFF + 1;
// d_ws float-element offsets
constexpr int WS_C2   = 0;      // [0,1024)   float ||c_k||^2 (numpy-bit-exact)
constexpr int WS_HIST = 1024;   // [1024,2048) uint  usage counts
constexpr int WS_LOSS = 2048;   // [2048]     float sum ||z-q||^2
constexpr float INV_TOTAL = 1.0f / (float)QELEMS;
constexpr float INV_NPOS  = 1.0f / (float)NPOS;
}

// Bit-exact replica of numpy pairwise_sum for n=128 contiguous float32 applied
// to elementwise squares: 8 accumulator chains (stride 8), sequential within a
// chain, combined ((r0+r1)+(r2+r3))+((r4+r5)+(r6+r7)). __f*_rn forbids fma
// contraction (numpy multiplies into a temp, then adds — never fused).
__device__ __forceinline__ float np_sumsq_128(const float* v) {
    float r[8];
    #pragma unroll
    for (int j = 0; j < 8; ++j) r[j] = __fmul_rn(v[j], v[j]);
    #pragma unroll
    for (int i = 8; i < 128; i += 8) {
        #pragma unroll
        for (int j = 0; j < 8; ++j)
            r[j] = __fadd_rn(r[j], __fmul_rn(v[i + j], v[i + j]));
    }
    const float s01 = __fadd_rn(r[0], r[1]);
    const float s23 = __fadd_rn(r[2], r[3]);
    const float s45 = __fadd_rn(r[4], r[5]);
    const float s67 = __fadd_rn(r[6], r[7]);
    return __fadd_rn(__fadd_rn(s01, s23), __fadd_rn(s45, s67));
}

// ---- pass 0: codebook norms (numpy-bit-exact) + zero accumulators ----------
__global__ __launch_bounds__(256) void vq_prep(const float* __restrict__ cb,
                                               float* __restrict__ ws) {
    const int k = blockIdx.x * 256 + threadIdx.x;   // 0..1023
    const float* row = cb + (size_t)k * CDIM;
    float rr[CDIM];
    #pragma unroll
    for (int c = 0; c < CDIM; ++c) rr[c] = row[c];
    ws[WS_C2 + k] = np_sumsq_128(rr);
    ((unsigned int*)ws)[WS_HIST + k] = 0u;
    if (k == 0) ws[WS_LOSS] = 0.0f;
}

// ---- pass 1: argmin, codebook via uniform scalar loads (no LDS tile) -------
// Round 4/5 post-mortem: LDS-broadcast codebook reads were the bottleneck
// (32768 ds_read_b128/wave x 12cyc = 656us of LDS pipe). Codebook operands are
// wave-uniform -> thread-invariant addresses compile to s_load through the
// scalar cache; v_fmac reads the SGPR as src0. Zero LDS data movement.
__global__ __launch_bounds__(256, 1) void vq_main(const float* __restrict__ z,
                                                  const float* __restrict__ cb,
                                                  float* __restrict__ ws,
                                                  float* __restrict__ out) {
    __shared__ unsigned int lhist[KCODES];            // 4 KB
    __shared__ float red[256];

    const int tid = threadIdx.x;
    const int n   = blockIdx.x * 256 + tid;
    const int b   = n >> 12;
    const int hw  = n & (HWSZ - 1);
    const float* zp  = z + (size_t)b * CDIM * HWSZ + hw;
    const float* c2g = ws + WS_C2;

    for (int i = tid; i < KCODES; i += 256) lhist[i] = 0u;
    __syncthreads();

    float zr[CDIM];
    #pragma unroll
    for (int c = 0; c < CDIM; ++c) zr[c] = zp[(size_t)c * HWSZ];

    // z2 bit-identical to np.sum(z_flat*z_flat, axis=1)
    const float z2 = np_sumsq_128(zr);

    float best_d = INFINITY;
    int   best_k = 0;

    for (int kb = 0; kb < KCODES; kb += 8) {
        const float* __restrict__ r0 = cb + (size_t)(kb + 0) * CDIM;
        const float* __restrict__ r1 = cb + (size_t)(kb + 1) * CDIM;
        const float* __restrict__ r2 = cb + (size_t)(kb + 2) * CDIM;
        const float* __restrict__ r3 = cb + (size_t)(kb + 3) * CDIM;
        const float* __restrict__ r4 = cb + (size_t)(kb + 4) * CDIM;
        const float* __restrict__ r5 = cb + (size_t)(kb + 5) * CDIM;
        const float* __restrict__ r6 = cb + (size_t)(kb + 6) * CDIM;
        const float* __restrict__ r7 = cb + (size_t)(kb + 7) * CDIM;
        // one sequential ascending-c fma chain per code (round-4 numerics)
        float a0 = 0.f, a1 = 0.f, a2 = 0.f, a3 = 0.f;
        float a4 = 0.f, a5 = 0.f, a6 = 0.f, a7 = 0.f;
        #pragma unroll
        for (int q = 0; q < CDIM / 4; ++q) {
            const float4 v0 = ((const float4*)r0)[q];
            const float4 v1 = ((const float4*)r1)[q];
            const float4 v2 = ((const float4*)r2)[q];
            const float4 v3 = ((const float4*)r3)[q];
            const float4 v4 = ((const float4*)r4)[q];
            const float4 v5 = ((const float4*)r5)[q];
            const float4 v6 = ((const float4*)r6)[q];
            const float4 v7 = ((const float4*)r7)[q];
            const float zx = zr[4*q+0], zy = zr[4*q+1];
            const float zz = zr[4*q+2], zw = zr[4*q+3];
            a0 = fmaf(v0.x, zx, a0); a0 = fmaf(v0.y, zy, a0);
            a0 = fmaf(v0.z, zz, a0); a0 = fmaf(v0.w, zw, a0);
            a1 = fmaf(v1.x, zx, a1); a1 = fmaf(v1.y, zy, a1);
            a1 = fmaf(v1.z, zz, a1); a1 = fmaf(v1.w, zw, a1);
            a2 = fmaf(v2.x, zx, a2); a2 = fmaf(v2.y, zy, a2);
            a2 = fmaf(v2.z, zz, a2); a2 = fmaf(v2.w, zw, a2);
            a3 = fmaf(v3.x, zx, a3); a3 = fmaf(v3.y, zy, a3);
            a3 = fmaf(v3.z, zz, a3); a3 = fmaf(v3.w, zw, a3);
            a4 = fmaf(v4.x, zx, a4); a4 = fmaf(v4.y, zy, a4);
            a4 = fmaf(v4.z, zz, a4); a4 = fmaf(v4.w, zw, a4);
            a5 = fmaf(v5.x, zx, a5); a5 = fmaf(v5.y, zy, a5);
            a5 = fmaf(v5.z, zz, a5); a5 = fmaf(v5.w, zw, a5);
            a6 = fmaf(v6.x, zx, a6); a6 = fmaf(v6.y, zy, a6);
            a6 = fmaf(v6.z, zz, a6); a6 = fmaf(v6.w, zw, a6);
            a7 = fmaf(v7.x, zx, a7); a7 = fmaf(v7.y, zy, a7);
            a7 = fmaf(v7.z, zz, a7); a7 = fmaf(v7.w, zw, a7);
        }
        // d = fl(fl(z2 - 2*zc) + c2): fmaf(-2,a,z2) == fl(z2-2a) since 2a
        // exact; __fadd_rn forbids contraction of the final add.
        const float d0 = __fadd_rn(fmaf(-2.0f, a0, z2), c2g[kb + 0]);
        const float d1 = __fadd_rn(fmaf(-2.0f, a1, z2), c2g[kb + 1]);
        const float d2 = __fadd_rn(fmaf(-2.0f, a2, z2), c2g[kb + 2]);
        const float d3 = __fadd_rn(fmaf(-2.0f, a3, z2), c2g[kb + 3]);
        const float d4 = __fadd_rn(fmaf(-2.0f, a4, z2), c2g[kb + 4]);
        const float d5 = __fadd_rn(fmaf(-2.0f, a5, z2), c2g[kb + 5]);
        const float d6 = __fadd_rn(fmaf(-2.0f, a6, z2), c2g[kb + 6]);
        const float d7 = __fadd_rn(fmaf(-2.0f, a7, z2), c2g[kb + 7]);
        // strict < ascending k == np.argmin first-index tie-break
        if (d0 < best_d) { best_d = d0; best_k = kb + 0; }
        if (d1 < best_d) { best_d = d1; best_k = kb + 1; }
        if (d2 < best_d) { best_d = d2; best_k = kb + 2; }
        if (d3 < best_d) { best_d = d3; best_k = kb + 3; }
        if (d4 < best_d) { best_d = d4; best_k = kb + 4; }
        if (d5 < best_d) { best_d = d5; best_k = kb + 5; }
        if (d6 < best_d) { best_d = d6; best_k = kb + 6; }
        if (d7 < best_d) { best_d = d7; best_k = kb + 7; }
    }

    // quantized output: fp32 gather of winning codebook row
    const float4* q4 = (const float4*)(cb + (size_t)best_k * CDIM);
    float* op = out + (size_t)b * CDIM * HWSZ + hw;
    #pragma unroll
    for (int q = 0; q < CDIM / 4; ++q) {
        const float4 v = q4[q];
        op[(size_t)(4 * q + 0) * HWSZ] = v.x;
        op[(size_t)(4 * q + 1) * HWSZ] = v.y;
        op[(size_t)(4 * q + 2) * HWSZ] = v.z;
        op[(size_t)(4 * q + 3) * HWSZ] = v.w;
    }

    // index output (fp32)
    out[IDX_OFF + (size_t)n] = (float)best_k;

    // loss: best_d == fl(||z-q||^2), ~128 magnitude, 2% slack
    atomicAdd(&lhist[best_k], 1u);
    red[tid] = best_d;
    __syncthreads();
    for (int s = 128; s > 0; s >>= 1) {
        if (tid < s) red[tid] += red[tid + s];
        __syncthreads();
    }
    if (tid == 0) atomicAdd(&ws[WS_LOSS], red[0]);

    unsigned int* ghist = (unsigned int*)ws + WS_HIST;
    for (int i = tid; i < KCODES; i += 256) {
        const unsigned int v = lhist[i];
        if (v) atomicAdd(&ghist[i], v);
    }
}

// ---- pass 2: scalars --------------------------------------------------------
__global__ __launch_bounds__(1024) void vq_final(const float* __restrict__ ws,
                                                 float* __restrict__ out) {
    __shared__ float red[1024];
    const int t = threadIdx.x;
    const unsigned int* hist = (const unsigned int*)ws + WS_HIST;
    const float p = (float)hist[t] * INV_NPOS;
    red[t] = p * logf(p + 1e-10f);
    __syncthreads();
    for (int s = 512; s > 0; s >>= 1) {
        if (t < s) red[t] += red[t + s];
        __syncthreads();
    }
    if (t == 0) {
        out[LOSS_OFF] = 1.25f * (ws[WS_LOSS] * INV_TOTAL);   // cb + 0.25*commit
        out[PERP_OFF] = expf(-red[0]);
    }
}

extern "C" void kernel_launch(void* const* d_in, const int* in_sizes, int n_in,
                              void* d_out, int out_size, void* d_ws, size_t ws_size,
                              hipStream_t stream) {
    const float* z  = (const float*)d_in[0];
    const float* cb = (const float*)d_in[1];
    float* out = (float*)d_out;
    float* ws  = (float*)d_ws;

    vq_prep <<<KCODES / 256, 256, 0, stream>>>(cb, ws);
    vq_main <<<NPOS / 256,   256, 0, stream>>>(z, cb, ws, out);
    vq_final<<<1,           1024, 0, stream>>>(ws, out);
}

// Round 7
// 1012.628 us; speedup vs baseline: 1.3030x; 1.3030x over previous
//
#include <hip/hip_runtime.h>
#include <hip/hip_bf16.h>
#include <math.h>

namespace {
constexpr int CDIM   = 128;
constexpr int KCODES = 1024;
constexpr int HWSZ   = 4096;   // 64*64
constexpr int BATCH  = 16;
constexpr int NPOS   = BATCH * HWSZ;            // 65536
constexpr size_t QELEMS   = (size_t)BATCH * CDIM * HWSZ;   // 8388608
constexpr size_t IDX_OFF  = QELEMS;                        // float32 elements
constexpr size_t LOSS_OFF = IDX_OFF + (size_t)NPOS;        // 8454144
constexpr size_t PERP_OFF = LOSS_OFF + 1;
// d_ws float-element offsets
constexpr int WS_C2   = 0;      // [0,1024)   float ||c_k||^2 (numpy-bit-exact)
constexpr int WS_HIST = 1024;   // [1024,2048) uint  usage counts
constexpr int WS_LOSS = 2048;   // [2048]     float sum ||z-q||^2
constexpr float INV_TOTAL = 1.0f / (float)QELEMS;
constexpr float INV_NPOS  = 1.0f / (float)NPOS;
}

// Bit-exact replica of numpy pairwise_sum for n=128 contiguous float32 applied
// to elementwise squares: 8 accumulator chains (stride 8), sequential within a
// chain, combined ((r0+r1)+(r2+r3))+((r4+r5)+(r6+r7)). __f*_rn forbids fma
// contraction (numpy multiplies into a temp, then adds — never fused).
__device__ __forceinline__ float np_sumsq_128(const float* v) {
    float r[8];
    #pragma unroll
    for (int j = 0; j < 8; ++j) r[j] = __fmul_rn(v[j], v[j]);
    #pragma unroll
    for (int i = 8; i < 128; i += 8) {
        #pragma unroll
        for (int j = 0; j < 8; ++j)
            r[j] = __fadd_rn(r[j], __fmul_rn(v[i + j], v[i + j]));
    }
    const float s01 = __fadd_rn(r[0], r[1]);
    const float s23 = __fadd_rn(r[2], r[3]);
    const float s45 = __fadd_rn(r[4], r[5]);
    const float s67 = __fadd_rn(r[6], r[7]);
    return __fadd_rn(__fadd_rn(s01, s23), __fadd_rn(s45, s67));
}

// ---- pass 0: codebook norms (numpy-bit-exact) + zero accumulators ----------
__global__ __launch_bounds__(256) void vq_prep(const float* __restrict__ cb,
                                               float* __restrict__ ws) {
    const int k = blockIdx.x * 256 + threadIdx.x;   // 0..1023
    const float* row = cb + (size_t)k * CDIM;
    float rr[CDIM];
    #pragma unroll
    for (int c = 0; c < CDIM; ++c) rr[c] = row[c];
    ws[WS_C2 + k] = np_sumsq_128(rr);
    ((unsigned int*)ws)[WS_HIST + k] = 0u;
    if (k == 0) ws[WS_LOSS] = 0.0f;
}

// ---- pass 1: GEMM-tiled argmin -------------------------------------------
// Block: 64 positions, z-tile in LDS shared by 4 waves; waves K-split codes
// (wave w -> [256w,256w+256)). Lane = 16 pos-groups x 4 code-lanes; thread
// tile 4 pos x 16 codes. Per channel-quad: 4 LDS b128 + 16 global b128 feed
// 256 FMAs -> LDS pipe ~98K cyc/CU vs FMA 262K cyc/CU (r4 was 1.57M LDS).
// Numerics: per-(n,k) dot = one sequential ascending-c fmaf chain (round-4
// verified); d = __fadd_rn(fmaf(-2,a,z2),c2); argmin predicate is order-free
// (d<bd)||(d==bd&&k<bk) == np.argmin first-index.
__global__ __launch_bounds__(256, 2) void vq_main(const float* __restrict__ z,
                                                  const float* __restrict__ cb,
                                                  float* __restrict__ ws,
                                                  float* __restrict__ out) {
    __shared__ __align__(16) float4 zt4[CDIM * 16];   // [c][poslane] 32 KB
    __shared__ float  z2s[64];
    __shared__ float  dbuf[256];
    __shared__ int    kbuf[256];
    __shared__ unsigned int lhist[KCODES];            // 4 KB

    const int tid      = threadIdx.x;
    const int lane     = tid & 63;
    const int w        = tid >> 6;        // wave 0..3 -> code range
    const int poslane  = lane >> 2;       // 0..15
    const int codelane = lane & 3;        // 0..3
    const int blk      = blockIdx.x;      // 0..1023
    const int n0       = blk * 64;
    const int b        = n0 >> 12;
    const int hw0      = n0 & (HWSZ - 1);

    // stage z tile ([c][64 pos] as float4 over positions) + zero hist
    const float4* zsrc = (const float4*)(z + (size_t)b * CDIM * HWSZ + hw0);
    #pragma unroll
    for (int i = 0; i < 8; ++i) {
        const int idx = i * 256 + tid;            // 0..2047
        const int c = idx >> 4, q = idx & 15;
        zt4[idx] = zsrc[(size_t)c * (HWSZ / 4) + q];
    }
    for (int i = tid; i < KCODES; i += 256) lhist[i] = 0u;
    __syncthreads();

    // z2 per position (numpy pairwise chain, bit-exact)
    if (tid < 64) {
        float rr[CDIM];
        #pragma unroll
        for (int c = 0; c < CDIM; ++c) rr[c] = ((const float*)zt4)[c * 64 + tid];
        z2s[tid] = np_sumsq_128(rr);
    }
    __syncthreads();

    float z2v[4];
    #pragma unroll
    for (int i = 0; i < 4; ++i) z2v[i] = z2s[poslane * 4 + i];

    const float* c2g = ws + WS_C2;
    float bd[4]; int bk[4];
    #pragma unroll
    for (int i = 0; i < 4; ++i) { bd[i] = INFINITY; bk[i] = 0; }

    for (int s = 0; s < 4; ++s) {
        const int k0 = w * 256 + s * 64 + codelane * 16;   // thread's 16 codes
        const float4* pcb = (const float4*)cb + (size_t)k0 * 32;  // [code][cq]
        float acc[4][16];
        #pragma unroll
        for (int i = 0; i < 4; ++i)
            #pragma unroll
            for (int j = 0; j < 16; ++j) acc[i][j] = 0.0f;

        #pragma unroll 2
        for (int cq = 0; cq < 32; ++cq) {
            const float4 zv0 = zt4[(cq * 4 + 0) * 16 + poslane];
            const float4 zv1 = zt4[(cq * 4 + 1) * 16 + poslane];
            const float4 zv2 = zt4[(cq * 4 + 2) * 16 + poslane];
            const float4 zv3 = zt4[(cq * 4 + 3) * 16 + poslane];
            const float za0[4] = {zv0.x, zv0.y, zv0.z, zv0.w};  // [pos] ch c+0
            const float za1[4] = {zv1.x, zv1.y, zv1.z, zv1.w};  // ch c+1
            const float za2[4] = {zv2.x, zv2.y, zv2.z, zv2.w};  // ch c+2
            const float za3[4] = {zv3.x, zv3.y, zv3.z, zv3.w};  // ch c+3
            #pragma unroll
            for (int j = 0; j < 16; ++j) {
                const float4 cv = pcb[(size_t)j * 32 + cq];
                #pragma unroll
                for (int i = 0; i < 4; ++i) {
                    // ascending-c sequential chain per (pos,code)
                    acc[i][j] = fmaf(cv.x, za0[i], acc[i][j]);
                    acc[i][j] = fmaf(cv.y, za1[i], acc[i][j]);
                    acc[i][j] = fmaf(cv.z, za2[i], acc[i][j]);
                    acc[i][j] = fmaf(cv.w, za3[i], acc[i][j]);
                }
            }
        }
        #pragma unroll
        for (int j = 0; j < 16; ++j) {
            const int k = k0 + j;
            const float c2 = c2g[k];
            #pragma unroll
            for (int i = 0; i < 4; ++i) {
                const float d = __fadd_rn(fmaf(-2.0f, acc[i][j], z2v[i]), c2);
                if (d < bd[i] || (d == bd[i] && k < bk[i])) { bd[i] = d; bk[i] = k; }
            }
        }
    }

    // reduce across the 4 code-lanes sharing these positions (lanes xor 1,2)
    #pragma unroll
    for (int m = 1; m <= 2; m <<= 1) {
        #pragma unroll
        for (int i = 0; i < 4; ++i) {
            const float od = __shfl_xor(bd[i], m);
            const int   ok = __shfl_xor(bk[i], m);
            if (od < bd[i] || (od == bd[i] && ok < bk[i])) { bd[i] = od; bk[i] = ok; }
        }
    }
    if (codelane == 0) {
        #pragma unroll
        for (int i = 0; i < 4; ++i) {
            dbuf[w * 64 + poslane * 4 + i] = bd[i];
            kbuf[w * 64 + poslane * 4 + i] = bk[i];
        }
    }
    __syncthreads();

    // combine the 4 waves' code ranges; epilogue by threads 0..63 (= wave 0)
    if (tid < 64) {
        float fd = dbuf[tid]; int fk = kbuf[tid];
        #pragma unroll
        for (int ww = 1; ww < 4; ++ww) {
            const float od = dbuf[ww * 64 + tid];
            const int   ok = kbuf[ww * 64 + tid];
            if (od < fd || (od == fd && ok < fk)) { fd = od; fk = ok; }
        }
        out[IDX_OFF + (size_t)(n0 + tid)] = (float)fk;

        const float4* q4 = (const float4*)(cb + (size_t)fk * CDIM);
        float* op = out + (size_t)b * CDIM * HWSZ + hw0 + tid;
        #pragma unroll
        for (int q = 0; q < CDIM / 4; ++q) {
            const float4 v = q4[q];
            op[(size_t)(4 * q + 0) * HWSZ] = v.x;
            op[(size_t)(4 * q + 1) * HWSZ] = v.y;
            op[(size_t)(4 * q + 2) * HWSZ] = v.z;
            op[(size_t)(4 * q + 3) * HWSZ] = v.w;
        }
        atomicAdd(&lhist[fk], 1u);

        float sum = fd;                     // loss: fd == fl(||z-q||^2), 2% slack
        #pragma unroll
        for (int m = 1; m < 64; m <<= 1) sum += __shfl_xor(sum, m);
        if (tid == 0) atomicAdd(&ws[WS_LOSS], sum);
    }
    __syncthreads();

    unsigned int* ghist = (unsigned int*)ws + WS_HIST;
    for (int i = tid; i < KCODES; i += 256) {
        const unsigned int v = lhist[i];
        if (v) atomicAdd(&ghist[i], v);
    }
}

// ---- pass 2: scalars --------------------------------------------------------
__global__ __launch_bounds__(1024) void vq_final(const float* __restrict__ ws,
                                                 float* __restrict__ out) {
    __shared__ float red[1024];
    const int t = threadIdx.x;
    const unsigned int* hist = (const unsigned int*)ws + WS_HIST;
    const float p = (float)hist[t] * INV_NPOS;
    red[t] = p * logf(p + 1e-10f);
    __syncthreads();
    for (int s = 512; s > 0; s >>= 1) {
        if (t < s) red[t] += red[t + s];
        __syncthreads();
    }
    if (t == 0) {
        out[LOSS_OFF] = 1.25f * (ws[WS_LOSS] * INV_TOTAL);   // cb + 0.25*commit
        out[PERP_OFF] = expf(-red[0]);
    }
}

extern "C" void kernel_launch(void* const* d_in, const int* in_sizes, int n_in,
                              void* d_out, int out_size, void* d_ws, size_t ws_size,
                              hipStream_t stream) {
    const float* z  = (const float*)d_in[0];
    const float* cb = (const float*)d_in[1];
    float* out = (float*)d_out;
    float* ws  = (float*)d_ws;

    vq_prep <<<KCODES / 256, 256, 0, stream>>>(cb, ws);
    vq_main <<<NPOS / 64,    256, 0, stream>>>(z, cb, ws, out);
    vq_final<<<1,           1024, 0, stream>>>(ws, out);
}